// Round 1
// baseline (17329.378 us; speedup 1.0000x reference)
//
#include <hip/hip_runtime.h>
#include <math.h>

#define N 150
#define NPAD 151
#define BLOCK 256
#define ITERS 100

#define PI_F 3.14159265358979323846f
#define TWO_PI_F 6.28318530717958647692f
#define EPS_F 1e-16f
// SINKHORN_EPS = 0.05 ; work in base-2 log domain:
// K = C / (eps*ln2); result scale = eps*ln2
#define EPSLN2 0.03465735902799726f      // 0.05 * ln(2)
#define INV_EPSLN2 28.853900817779268f   // 1 / (0.05*ln2)

#if __has_builtin(__builtin_amdgcn_exp2f)
#define FEXP2(x) __builtin_amdgcn_exp2f(x)
#else
#define FEXP2(x) exp2f(x)
#endif
#if __has_builtin(__builtin_amdgcn_logf)
#define FLOG2(x) __builtin_amdgcn_logf(x)
#else
#define FLOG2(x) log2f(x)
#endif

__device__ __forceinline__ float blockReduceSum(float v, float* red) {
    // wave-64 reduce
    for (int o = 32; o > 0; o >>= 1) v += __shfl_down(v, o, 64);
    const int lane = threadIdx.x & 63;
    const int wv = threadIdx.x >> 6;
    __syncthreads();              // protect red[] from previous use
    if (lane == 0) red[wv] = v;
    __syncthreads();
    return red[0] + red[1] + red[2] + red[3];   // BLOCK==256 -> 4 waves
}

__global__ __launch_bounds__(BLOCK, 1) void emd_kernel(
    const float* __restrict__ p_recons,
    const float* __restrict__ p_target,
    float* __restrict__ out)
{
    __shared__ float K[N * NPAD];                 // 90600 B
    __shared__ float xeta[N], xphi[N];
    __shared__ float yeta[N], yphi[N];
    __shared__ float l2a[N], l2b[N];
    __shared__ float uu[N], vv[N];
    __shared__ float red[4];

    const int b = blockIdx.x;
    const int tid = threadIdx.x;

    // ---- coordinate transform for both clouds ----
    for (int c = 0; c < 2; ++c) {
        const float* P = (c == 0 ? p_recons : p_target) + (size_t)b * (N * 3);
        float px = 0.f, py = 0.f, pz = 0.f;
        if (tid < N) {
            px = P[tid * 3 + 0];
            py = P[tid * 3 + 1];
            pz = P[tid * 3 + 2];
        }
        const float jx = blockReduceSum(px, red);
        const float jy = blockReduceSum(py, red);
        const float jz = blockReduceSum(pz, red);
        const float jpt  = sqrtf(jx * jx + jy * jy + EPS_F);
        const float jphi = atan2f(jy + EPS_F, jx + EPS_F);
        const float jeta = asinhf(jz / (jpt + EPS_F));

        float ptrel = 0.f, erel = 0.f, prel = 0.f;
        if (tid < N) {
            const float pt  = sqrtf(px * px + py * py + EPS_F);
            const float phi = atan2f(py + EPS_F, px + EPS_F);
            const float eta = asinhf(pz / (pt + EPS_F));
            erel = eta - jeta;
            float d = phi - jphi + PI_F;
            d = fmodf(d, TWO_PI_F);        // JAX % is floor-mod
            if (d < 0.f) d += TWO_PI_F;
            prel = d - PI_F;
            ptrel = pt / (jpt + EPS_F);
        }
        const float spt = blockReduceSum(ptrel, red);
        if (tid < N) {
            const float aa = ptrel / (spt + EPS_F);
            if (c == 0) { xeta[tid] = erel; xphi[tid] = prel; l2a[tid] = FLOG2(aa + EPS_F); }
            else        { yeta[tid] = erel; yphi[tid] = prel; l2b[tid] = FLOG2(aa + EPS_F); }
        }
    }
    __syncthreads();

    // ---- build K = C/(eps*ln2), row-major stride NPAD ----
    for (int idx = tid; idx < N * N; idx += BLOCK) {
        const int i = idx / N;
        const int j = idx - i * N;
        const float de = xeta[i] - yeta[j];
        const float dp = xphi[i] - yphi[j];
        K[i * NPAD + j] = sqrtf(de * de + dp * dp + EPS_F) * INV_EPSLN2;
    }
    if (tid < N) { uu[tid] = 0.f; vv[tid] = 0.f; }
    __syncthreads();

    // ---- Sinkhorn iterations (base-2 log domain) ----
    for (int it = 0; it < ITERS; ++it) {
        // u_i = log2(a_i) - l2se_j(v_j - K[i][j])   (thread-per-row)
        if (tid < N) {
            const float* Krow = &K[tid * NPAD];
            float m = -1e30f;
            #pragma unroll 5
            for (int j = 0; j < N; ++j) m = fmaxf(m, vv[j] - Krow[j]);
            float s = 0.f;
            #pragma unroll 5
            for (int j = 0; j < N; ++j) s += FEXP2(vv[j] - Krow[j] - m);
            uu[tid] = l2a[tid] - (m + FLOG2(s));
        }
        __syncthreads();
        // v_j = log2(b_j) - l2se_i(u_i - K[i][j])   (thread-per-col)
        if (tid < N) {
            float m = -1e30f;
            #pragma unroll 5
            for (int i = 0; i < N; ++i) m = fmaxf(m, uu[i] - K[i * NPAD + tid]);
            float s = 0.f;
            #pragma unroll 5
            for (int i = 0; i < N; ++i) s += FEXP2(uu[i] - K[i * NPAD + tid] - m);
            vv[tid] = l2b[tid] - (m + FLOG2(s));
        }
        __syncthreads();
    }

    // ---- result: eps*ln2 * sum_ij 2^(u_i+v_j-K_ij) * K_ij ----
    float part = 0.f;
    if (tid < N) {
        const float* Krow = &K[tid * NPAD];
        const float ui = uu[tid];
        #pragma unroll 5
        for (int j = 0; j < N; ++j) {
            const float k = Krow[j];
            part += FEXP2(ui + vv[j] - k) * k;
        }
    }
    part = blockReduceSum(part, red);
    if (tid == 0) atomicAdd(out, part * EPSLN2);
}

extern "C" void kernel_launch(void* const* d_in, const int* in_sizes, int n_in,
                              void* d_out, int out_size, void* d_ws, size_t ws_size,
                              hipStream_t stream) {
    const float* pr = (const float*)d_in[0];
    const float* pt = (const float*)d_in[1];
    float* out = (float*)d_out;
    const int B = in_sizes[0] / (N * 3);
    hipMemsetAsync(d_out, 0, sizeof(float) * out_size, stream);
    hipLaunchKernelGGL(emd_kernel, dim3(B), dim3(BLOCK), 0, stream, pr, pt, out);
}

// Round 2
// 3714.692 us; speedup vs baseline: 4.6651x; 4.6651x over previous
//
#include <hip/hip_runtime.h>
#include <hip/hip_fp16.h>
#include <math.h>

#define N 150
#define NP 152          // padded logical dim (2 pad rows/cols with huge cost)
#define HALF_NP 76
#define STRIDE 154      // fp16 row stride: 154*2B=308B -> lane bank stride 77 (odd) = conflict-free
#define BLOCK 320       // 5 waves; 2 workers per row (300 active)
#define ITERS 100
#define WARM 5          // two-pass logsumexp for first WARM iters, then single-pass w/ tracked max
#define BIGK 60000.0f   // pad cost (fp16-representable)
#define NEGBIG -60000.0f

#define PI_F 3.14159265358979323846f
#define TWO_PI_F 6.28318530717958647692f
#define EPS_F 1e-16f
// SINKHORN_EPS = 0.05 ; base-2 log domain: K = C/(eps*ln2), result scale eps*ln2
#define EPSLN2 0.03465735902799726f
#define INV_EPSLN2 28.853900817779268f

#if __has_builtin(__builtin_amdgcn_exp2f)
#define FEXP2(x) __builtin_amdgcn_exp2f(x)
#else
#define FEXP2(x) exp2f(x)
#endif
#if __has_builtin(__builtin_amdgcn_logf)
#define FLOG2(x) __builtin_amdgcn_logf(x)
#else
#define FLOG2(x) log2f(x)
#endif

__device__ __forceinline__ float blockReduceSum(float v, float* red) {
    for (int o = 32; o > 0; o >>= 1) v += __shfl_down(v, o, 64);
    const int lane = threadIdx.x & 63;
    const int wv = threadIdx.x >> 6;
    __syncthreads();
    if (lane == 0) red[wv] = v;
    __syncthreads();
    return red[0] + red[1] + red[2] + red[3] + red[4];  // 5 waves
}

__global__ __launch_bounds__(BLOCK, 4) void emd_kernel(
    const float* __restrict__ p_recons,
    const float* __restrict__ p_target,
    float* __restrict__ out)
{
    __shared__ __align__(16) __half Kh[NP * STRIDE];   // 46816 B
    __shared__ float xeta[N], xphi[N], yeta[N], yphi[N];
    __shared__ float l2a[NP], l2b[NP];
    __shared__ __align__(16) float uu[NP];
    __shared__ __align__(16) float vv[NP];
    __shared__ float mrow[N], mcol[N];
    __shared__ float red[5];
    // total ~52.9 KB -> 3 blocks/CU

    const int b = blockIdx.x;
    const int tid = threadIdx.x;

    // ---- coordinate transform (both clouds) ----
    for (int c = 0; c < 2; ++c) {
        const float* P = (c == 0 ? p_recons : p_target) + (size_t)b * (N * 3);
        float px = 0.f, py = 0.f, pz = 0.f;
        if (tid < N) {
            px = P[tid * 3 + 0];
            py = P[tid * 3 + 1];
            pz = P[tid * 3 + 2];
        }
        const float jx = blockReduceSum(px, red);
        const float jy = blockReduceSum(py, red);
        const float jz = blockReduceSum(pz, red);
        const float jpt  = sqrtf(jx * jx + jy * jy + EPS_F);
        const float jphi = atan2f(jy + EPS_F, jx + EPS_F);
        const float jeta = asinhf(jz / (jpt + EPS_F));

        float ptrel = 0.f, erel = 0.f, prel = 0.f;
        if (tid < N) {
            const float pt  = sqrtf(px * px + py * py + EPS_F);
            const float phi = atan2f(py + EPS_F, px + EPS_F);
            const float eta = asinhf(pz / (pt + EPS_F));
            erel = eta - jeta;
            float d = phi - jphi + PI_F;
            d = fmodf(d, TWO_PI_F);            // JAX % is floor-mod
            if (d < 0.f) d += TWO_PI_F;
            prel = d - PI_F;
            ptrel = pt / (jpt + EPS_F);
        }
        const float spt = blockReduceSum(ptrel, red);
        if (tid < N) {
            const float aa = ptrel / (spt + EPS_F);
            if (c == 0) { xeta[tid] = erel; xphi[tid] = prel; l2a[tid] = FLOG2(aa + EPS_F); }
            else        { yeta[tid] = erel; yphi[tid] = prel; l2b[tid] = FLOG2(aa + EPS_F); }
        }
    }
    __syncthreads();

    // ---- build padded fp16 K ----
    for (int idx = tid; idx < NP * NP; idx += BLOCK) {
        const int i = idx / NP;
        const int j = idx - i * NP;
        float val;
        if (i < N && j < N) {
            const float de = xeta[i] - yeta[j];
            const float dp = xphi[i] - yphi[j];
            val = sqrtf(de * de + dp * dp + EPS_F) * INV_EPSLN2;
        } else {
            val = BIGK;   // pad row/col: contributes exp2(~-1.2e5)=0, never the max
        }
        Kh[i * STRIDE + j] = __float2half(val);
    }
    if (tid < NP) {
        const float z = (tid < N) ? 0.f : NEGBIG;
        uu[tid] = z; vv[tid] = z;   // pads stay NEGBIG forever
    }
    __syncthreads();

    // ---- Sinkhorn ----
    for (int it = 0; it < ITERS; ++it) {
        const bool warm = (it < WARM);

        // u-pass: 2 workers per row, halves of 76 cols, K as __half2 pairs
        if (tid < 2 * N) {
            const int r = tid >> 1, h = tid & 1;
            const __half2* Krow = (const __half2*)&Kh[r * STRIDE + h * HALF_NP];
            const float2*  vvp  = (const float2*)&vv[h * HALF_NP];
            float m;
            if (warm) {
                float mx = -1e30f;
                #pragma unroll 8
                for (int s = 0; s < HALF_NP / 2; ++s) {
                    const float2 kv = __half22float2(Krow[s]);
                    const float2 vp = vvp[s];
                    mx = fmaxf(mx, fmaxf(vp.x - kv.x, vp.y - kv.y));
                }
                mx = fmaxf(mx, __shfl_xor(mx, 1, 64));
                m = mx;
            } else {
                m = mrow[r];   // prev-iter max: exact offset (LSE is offset-invariant)
            }
            float s = 0.f, mx = -1e30f;
            #pragma unroll 8
            for (int si = 0; si < HALF_NP / 2; ++si) {
                const float2 kv = __half22float2(Krow[si]);
                const float2 vp = vvp[si];
                const float t0 = vp.x - kv.x;
                const float t1 = vp.y - kv.y;
                s += FEXP2(fminf(t0 - m, 125.f)) + FEXP2(fminf(t1 - m, 125.f));
                mx = fmaxf(mx, fmaxf(t0, t1));
            }
            s  += __shfl_xor(s, 1, 64);
            mx  = fmaxf(mx, __shfl_xor(mx, 1, 64));
            if (h == 0) {
                uu[r]   = l2a[r] - (m + FLOG2(fmaxf(s, 1e-37f)));
                mrow[r] = mx;
            }
        }
        __syncthreads();

        // v-pass: 1 worker per (col-pair, half): lanes read contiguous __half2
        if (tid < N) {
            const int p = tid >> 1, h = tid & 1;
            const int c0 = 2 * p;
            float m0, m1;
            if (warm) {
                float a0 = -1e30f, a1 = -1e30f;
                #pragma unroll 8
                for (int si = 0; si < HALF_NP; ++si) {
                    const int i = h * HALF_NP + si;
                    const float2 kv = __half22float2(*(const __half2*)&Kh[i * STRIDE + c0]);
                    const float ui = uu[i];
                    a0 = fmaxf(a0, ui - kv.x);
                    a1 = fmaxf(a1, ui - kv.y);
                }
                a0 = fmaxf(a0, __shfl_xor(a0, 1, 64));
                a1 = fmaxf(a1, __shfl_xor(a1, 1, 64));
                m0 = a0; m1 = a1;
            } else {
                m0 = mcol[c0]; m1 = mcol[c0 + 1];
            }
            float s0 = 0.f, s1 = 0.f, x0 = -1e30f, x1 = -1e30f;
            #pragma unroll 8
            for (int si = 0; si < HALF_NP; ++si) {
                const int i = h * HALF_NP + si;
                const float2 kv = __half22float2(*(const __half2*)&Kh[i * STRIDE + c0]);
                const float ui = uu[i];
                const float t0 = ui - kv.x;
                const float t1 = ui - kv.y;
                s0 += FEXP2(fminf(t0 - m0, 125.f));
                s1 += FEXP2(fminf(t1 - m1, 125.f));
                x0 = fmaxf(x0, t0);
                x1 = fmaxf(x1, t1);
            }
            s0 += __shfl_xor(s0, 1, 64);
            s1 += __shfl_xor(s1, 1, 64);
            x0 = fmaxf(x0, __shfl_xor(x0, 1, 64));
            x1 = fmaxf(x1, __shfl_xor(x1, 1, 64));
            if (h == 0) {
                vv[c0]     = l2b[c0]     - (m0 + FLOG2(fmaxf(s0, 1e-37f)));
                vv[c0 + 1] = l2b[c0 + 1] - (m1 + FLOG2(fmaxf(s1, 1e-37f)));
                mcol[c0]     = x0;
                mcol[c0 + 1] = x1;
            }
        }
        __syncthreads();
    }

    // ---- EMD = eps*ln2 * sum exp2(u+v-K)*K ----
    float acc = 0.f;
    if (tid < 2 * N) {
        const int r = tid >> 1, h = tid & 1;
        const __half2* Krow = (const __half2*)&Kh[r * STRIDE + h * HALF_NP];
        const float2*  vvp  = (const float2*)&vv[h * HALF_NP];
        const float ur = uu[r];
        #pragma unroll 8
        for (int si = 0; si < HALF_NP / 2; ++si) {
            const float2 kv = __half22float2(Krow[si]);
            const float2 vp = vvp[si];
            acc += FEXP2(fminf(ur + vp.x - kv.x, 125.f)) * kv.x
                 + FEXP2(fminf(ur + vp.y - kv.y, 125.f)) * kv.y;
        }
    }
    acc = blockReduceSum(acc, red);
    if (tid == 0) atomicAdd(out, acc * EPSLN2);
}

extern "C" void kernel_launch(void* const* d_in, const int* in_sizes, int n_in,
                              void* d_out, int out_size, void* d_ws, size_t ws_size,
                              hipStream_t stream) {
    const float* pr = (const float*)d_in[0];
    const float* pt = (const float*)d_in[1];
    float* out = (float*)d_out;
    const int B = in_sizes[0] / (N * 3);
    hipMemsetAsync(d_out, 0, sizeof(float) * out_size, stream);
    hipLaunchKernelGGL(emd_kernel, dim3(B), dim3(BLOCK), 0, stream, pr, pt, out);
}